// Round 1
// baseline (102.287 us; speedup 1.0000x reference)
//
#include <hip/hip_runtime.h>

// state[e, g, t, c] = sum_{s<=t} param_1 * disp[e, s]
// -> cumsum over t (T=128), broadcast over g (8) and c (6).
// Output [E, 8, 128, 6] fp32: write-bound (491.5 MB writes vs 10.2 MB reads).

#define T_LEN 128
#define PER_ELEM (8 * T_LEN * 6)       // 6144 floats per element
#define PER_ELEM_V4 (PER_ELEM / 4)     // 1536 float4 per element

__global__ __launch_bounds__(256) void state_cumsum_bcast(
    const float* __restrict__ disp,    // [E, 128]
    const float* __restrict__ param1,  // [1]
    float* __restrict__ out,           // [E, 8, 128, 6]
    int n_elem) {
  __shared__ float cum[T_LEN];

  const int e = blockIdx.x;
  if (e >= n_elem) return;
  const int tid = threadIdx.x;

  if (tid < 64) {
    const float p = param1[0];
    const int lane = tid;
    // two 64-lane segments cover T=128; coalesced 256B loads
    float x0 = p * disp[(size_t)e * T_LEN + lane];
    float x1 = p * disp[(size_t)e * T_LEN + 64 + lane];
    // inclusive scan across 64 lanes (wave = 64 on CDNA)
    #pragma unroll
    for (int d = 1; d < 64; d <<= 1) {
      float y0 = __shfl_up(x0, d, 64);
      float y1 = __shfl_up(x1, d, 64);
      if (lane >= d) { x0 += y0; x1 += y1; }
    }
    const float total0 = __shfl(x0, 63, 64);
    cum[lane] = x0;
    cum[64 + lane] = x1 + total0;
  }
  __syncthreads();

  // Broadcast: each element's output is one contiguous 24 KB span.
  // float index f in [0, 6144): t = (f/6) % 128, value = cum[t].
  float4* o4 = reinterpret_cast<float4*>(out + (size_t)e * PER_ELEM);
  #pragma unroll
  for (int i = 0; i < PER_ELEM_V4 / 256; ++i) {
    const int v = i * 256 + tid;
    const int f = v * 4;
    float4 w;
    w.x = cum[((f + 0) / 6) & (T_LEN - 1)];
    w.y = cum[((f + 1) / 6) & (T_LEN - 1)];
    w.z = cum[((f + 2) / 6) & (T_LEN - 1)];
    w.w = cum[((f + 3) / 6) & (T_LEN - 1)];
    o4[v] = w;
  }
}

extern "C" void kernel_launch(void* const* d_in, const int* in_sizes, int n_in,
                              void* d_out, int out_size, void* d_ws, size_t ws_size,
                              hipStream_t stream) {
  const float* disp   = (const float*)d_in[0];  // [E, 128]
  const float* param1 = (const float*)d_in[1];  // [1]
  float* out = (float*)d_out;

  const int n_elem = in_sizes[0] / T_LEN;  // 20000

  state_cumsum_bcast<<<n_elem, 256, 0, stream>>>(disp, param1, out, n_elem);
}

// Round 3
// 95.427 us; speedup vs baseline: 1.0719x; 1.0719x over previous
//
#include <hip/hip_runtime.h>

// state[e, g, t, c] = sum_{s<=t} param_1 * disp[e, s]
// -> cumsum over t (T=128), broadcast over g (8) and c (6).
// Output [E, 8, 128, 6] fp32: write-bound (491.5 MB writes vs 10.2 MB reads).
// R3: nontemporal stores via native ext_vector float4 (HIP float4 class is
//     rejected by __builtin_nontemporal_store).

#define T_LEN 128
#define PER_ELEM (8 * T_LEN * 6)       // 6144 floats per element
#define PER_ELEM_V4 (PER_ELEM / 4)     // 1536 float4 per element

typedef float f32x4 __attribute__((ext_vector_type(4)));

__global__ __launch_bounds__(256) void state_cumsum_bcast(
    const float* __restrict__ disp,    // [E, 128]
    const float* __restrict__ param1,  // [1]
    float* __restrict__ out,           // [E, 8, 128, 6]
    int n_elem) {
  __shared__ float cum[T_LEN];

  const int e = blockIdx.x;
  if (e >= n_elem) return;
  const int tid = threadIdx.x;

  if (tid < 64) {
    const float p = param1[0];
    const int lane = tid;
    // two 64-lane segments cover T=128; coalesced 256B loads
    float x0 = p * disp[(size_t)e * T_LEN + lane];
    float x1 = p * disp[(size_t)e * T_LEN + 64 + lane];
    // inclusive scan across 64 lanes (wave = 64 on CDNA)
    #pragma unroll
    for (int d = 1; d < 64; d <<= 1) {
      float y0 = __shfl_up(x0, d, 64);
      float y1 = __shfl_up(x1, d, 64);
      if (lane >= d) { x0 += y0; x1 += y1; }
    }
    const float total0 = __shfl(x0, 63, 64);
    cum[lane] = x0;
    cum[64 + lane] = x1 + total0;
  }
  __syncthreads();

  // Broadcast: each element's output is one contiguous 24 KB span.
  // float index f in [0, 6144): t = (f/6) % 128, value = cum[t].
  f32x4* o4 = reinterpret_cast<f32x4*>(out + (size_t)e * PER_ELEM);
  #pragma unroll
  for (int i = 0; i < PER_ELEM_V4 / 256; ++i) {
    const int v = i * 256 + tid;
    const int f = v * 4;
    f32x4 w;
    w.x = cum[((f + 0) / 6) & (T_LEN - 1)];
    w.y = cum[((f + 1) / 6) & (T_LEN - 1)];
    w.z = cum[((f + 2) / 6) & (T_LEN - 1)];
    w.w = cum[((f + 3) / 6) & (T_LEN - 1)];
    __builtin_nontemporal_store(w, &o4[v]);
  }
}

extern "C" void kernel_launch(void* const* d_in, const int* in_sizes, int n_in,
                              void* d_out, int out_size, void* d_ws, size_t ws_size,
                              hipStream_t stream) {
  const float* disp   = (const float*)d_in[0];  // [E, 128]
  const float* param1 = (const float*)d_in[1];  // [1]
  float* out = (float*)d_out;

  const int n_elem = in_sizes[0] / T_LEN;  // 20000

  state_cumsum_bcast<<<n_elem, 256, 0, stream>>>(disp, param1, out, n_elem);
}